// Round 3
// baseline (1375.572 us; speedup 1.0000x reference)
//
#include <hip/hip_runtime.h>
#include <stdint.h>

typedef unsigned int u32;

#define S_DIM 2048
#define R_DIM 384
#define C_DIM 64

// float-offsets into d_ws (~3.74 MB used)
#define OFF_MASKT 0          // [384][2048] mask transposed, fp32
#define OFF_QRED  786432     // [384][4][64] per-wave qsum partials (k1-internal)
#define OFF_MSUM  884736     // [384][4]
#define OFF_QH    886272     // [384][64] scaled query
#define OFF_O     910848     // [384][64] per-column attention output o
// end: 935424 floats
// qred region is dead after k1 -> reuse it for fused-LN gate weights:
#define OFF_WG2   786432     // [64][64]  lnw[c]*wg[c][j]
#define OFF_CG    790528     // [64]      sum_c wg2[c][j]
#define OFF_DG    790592     // [64]      sum_c lnb[c]*wg[c][j] + bg[j]

__device__ __forceinline__ float bflo(u32 u){ return __uint_as_float(u << 16); }
__device__ __forceinline__ float bfhi(u32 u){ return __uint_as_float(u & 0xffff0000u); }
__device__ __forceinline__ u32 packbf2(float a, float b){
    u32 xa = __float_as_uint(a), xb = __float_as_uint(b);
    u32 ra = (xa + 0x7fffu + ((xa >> 16) & 1u)) >> 16;   // RNE
    u32 rb = (xb + 0x7fffu + ((xb >> 16) & 1u)) >> 16;
    return (ra & 0xffffu) | (rb << 16);
}
__device__ __forceinline__ void u4tof8(uint4 u, float* f){
    f[0]=bflo(u.x); f[1]=bfhi(u.x); f[2]=bflo(u.y); f[3]=bfhi(u.y);
    f[4]=bflo(u.z); f[5]=bfhi(u.z); f[6]=bflo(u.w); f[7]=bfhi(u.w);
}

// ---------------- prep: mask [S][R] fp32 -> [R][S] fp32 ----------------------------
__global__ void prep_mask(const float* __restrict__ mask, float* __restrict__ maskT)
{
    const int tid = blockIdx.x * 256 + threadIdx.x;   // over S*R, coalesced read
    const int s = tid / R_DIM;
    const int r = tid - s * R_DIM;
    maskT[(size_t)r * S_DIM + s] = mask[tid];
}

// ---------------- prep: fold LayerNorm into gate matmul ----------------------------
// wg2[c][j] = lnw[c]*wg[c][j]; cg[j] = sum_c wg2[c][j]; dg[j] = sum_c lnb[c]*wg[c][j] + bg[j]
__global__ void prep_w(const float* __restrict__ lnw, const float* __restrict__ lnb,
                       const float* __restrict__ wg,  const float* __restrict__ bg,
                       float* __restrict__ wg2, float* __restrict__ cg,
                       float* __restrict__ dg)
{
    const int j = threadIdx.x;   // 64
    float c_acc = 0.f, d_acc = 0.f;
    for (int c = 0; c < 64; ++c){
        float w  = wg[c*64 + j];
        float w2 = lnw[c] * w;
        wg2[c*64 + j] = w2;
        c_acc += w2;
        d_acc = fmaf(lnb[c], w, d_acc);
    }
    cg[j] = c_acc;
    dg[j] = d_acc + bg[j];
}

// ---------------- K1: per-column LN + k/v + pooled q + softmax + o ------------------
// one block per r; kv kept in LDS (bf16-packed), cross-wave scalars via global scratch
__global__ __launch_bounds__(256, 2) void k1_kv_softmax(
    const float* __restrict__ m,
    const float* __restrict__ lnw, const float* __restrict__ lnb,
    const float* __restrict__ wq,  const float* __restrict__ wk,
    const float* __restrict__ wv,
    const float* __restrict__ maskT,
    float* __restrict__ qred,
    float* __restrict__ msum,
    float* __restrict__ qh,
    float* __restrict__ otab)
{
    __shared__ uint4 kv[S_DIM * 2];   // exactly 64 KB: [s][0]=k bf16x8, [s][1]=v bf16x8

    const int t    = threadIdx.x;
    const int r    = blockIdx.x;
    const int w    = t >> 6;
    const int lane = t & 63;

    float qacc[64];
    #pragma unroll
    for (int c = 0; c < 64; ++c) qacc[c] = 0.f;
    float macc = 0.f;

    for (int it = 0; it < 8; ++it){
        const int s = it * 256 + t;
        const float4* mrow = reinterpret_cast<const float4*>(m + ((size_t)s * R_DIM + r) * C_DIM);
        float xn[64];
        #pragma unroll
        for (int q4 = 0; q4 < 16; ++q4){
            float4 f = mrow[q4];
            xn[q4*4+0]=f.x; xn[q4*4+1]=f.y; xn[q4*4+2]=f.z; xn[q4*4+3]=f.w;
        }

        float sm = 0.f, sq = 0.f;
        #pragma unroll
        for (int c = 0; c < 64; ++c){ sm += xn[c]; sq = fmaf(xn[c], xn[c], sq); }
        float mu  = sm * (1.f/64.f);
        float var = fmaf(-mu, mu, sq * (1.f/64.f));
        float rs  = rsqrtf(var + 1e-5f);
        #pragma unroll
        for (int c = 0; c < 64; ++c)
            xn[c] = fmaf((xn[c]-mu)*rs, lnw[c], lnb[c]);

        float mk = maskT[(size_t)r * S_DIM + s];
        macc += mk;
        #pragma unroll
        for (int c = 0; c < 64; ++c) qacc[c] = fmaf(xn[c], mk, qacc[c]);

        float kk[8], vv[8];
        #pragma unroll
        for (int ch = 0; ch < 8; ++ch){ kk[ch]=0.f; vv[ch]=0.f; }
        #pragma unroll
        for (int c = 0; c < 64; ++c){
            float xc = xn[c];
            #pragma unroll
            for (int ch = 0; ch < 8; ++ch){
                kk[ch] = fmaf(xc, wk[c*8 + ch], kk[ch]);
                vv[ch] = fmaf(xc, wv[c*8 + ch], vv[ch]);
            }
        }
        kv[s*2  ] = make_uint4(packbf2(kk[0],kk[1]),packbf2(kk[2],kk[3]),
                               packbf2(kk[4],kk[5]),packbf2(kk[6],kk[7]));
        kv[s*2+1] = make_uint4(packbf2(vv[0],vv[1]),packbf2(vv[2],vv[3]),
                               packbf2(vv[4],vv[5]),packbf2(vv[6],vv[7]));
    }

    // elementwise butterfly reduce qacc over the 64 lanes; lane c keeps channel c
    float myq = 0.f;
    #pragma unroll
    for (int c = 0; c < 64; ++c){
        float v = qacc[c];
        v += __shfl_xor(v, 1);  v += __shfl_xor(v, 2);  v += __shfl_xor(v, 4);
        v += __shfl_xor(v, 8);  v += __shfl_xor(v, 16); v += __shfl_xor(v, 32);
        myq = (lane == c) ? v : myq;
    }
    qred[r*256 + w*64 + lane] = myq;
    {
        float v = macc;
        v += __shfl_xor(v, 1);  v += __shfl_xor(v, 2);  v += __shfl_xor(v, 4);
        v += __shfl_xor(v, 8);  v += __shfl_xor(v, 16); v += __shfl_xor(v, 32);
        if (lane == 0) msum[r*4 + w] = v;
    }
    __threadfence_block();
    __syncthreads();

    // q = (masked-mean(xn) @ wq) * 8^-0.5     (volatile reads: bypass stale L1)
    volatile const float* vqred = qred;
    volatile const float* vmsum = msum;
    if (t < 64){
        float ms   = vmsum[r*4+0] + vmsum[r*4+1] + vmsum[r*4+2] + vmsum[r*4+3];
        float invD = 1.f / (ms + 1e-10f);
        float acc  = 0.f;
        for (int c = 0; c < 64; ++c){
            float qm = (vqred[r*256 + c] + vqred[r*256 + 64 + c] +
                        vqred[r*256 + 128 + c] + vqred[r*256 + 192 + c]) * invD;
            acc = fmaf(qm, wq[c*64 + t], acc);
        }
        qh[r*64 + t] = acc * 0.35355339059327373f;
    }
    __threadfence_block();
    __syncthreads();

    // per-head online softmax over s; 32 lanes per head
    volatile const float* vqh = qh;
    const int h   = t >> 5;
    const int sub = t & 31;
    float qv[8];
    #pragma unroll
    for (int j = 0; j < 8; ++j) qv[j] = vqh[r*64 + h*8 + j];

    float mx = -1e30f, ls = 0.f, oa[8];
    #pragma unroll
    for (int j = 0; j < 8; ++j) oa[j] = 0.f;

    for (int j2 = 0; j2 < 64; ++j2){
        const int s = j2*32 + sub;
        float kf[8]; u4tof8(kv[s*2], kf);
        float mk = maskT[(size_t)r * S_DIM + s];
        float logit = 1e9f * (mk - 1.f);
        #pragma unroll
        for (int j = 0; j < 8; ++j) logit = fmaf(qv[j], kf[j], logit);
        float nm = fmaxf(mx, logit);
        float p  = __expf(logit - nm);
        float cr = __expf(mx - nm);
        float vf[8]; u4tof8(kv[s*2+1], vf);
        ls = fmaf(ls, cr, p);
        #pragma unroll
        for (int j = 0; j < 8; ++j) oa[j] = fmaf(oa[j], cr, p * vf[j]);
        mx = nm;
    }
    #pragma unroll
    for (int xm = 16; xm >= 1; xm >>= 1){
        float m2 = __shfl_xor(mx, xm);
        float l2 = __shfl_xor(ls, xm);
        float nm = fmaxf(mx, m2);
        float c1 = __expf(mx - nm);
        float c2 = __expf(m2 - nm);
        ls = ls*c1 + l2*c2;
        #pragma unroll
        for (int j = 0; j < 8; ++j){
            float o2 = __shfl_xor(oa[j], xm);
            oa[j] = oa[j]*c1 + o2*c2;
        }
        mx = nm;
    }
    if (sub == 0){
        float inv = 1.f / ls;
        #pragma unroll
        for (int j = 0; j < 8; ++j) otab[r*64 + h*8 + j] = oa[j] * inv;
    }
}

// ---------------- K2: fused-LN gate + output projection, split-row ------------------
// Two threads per (s,r) row: wave w of 4 handles channel-half (w&1) of 64 rows
// (lane = row). Live set per thread: raw[32] then acc[32] -> ~48 VGPRs, cannot spill.
// hf is wave-uniform so wg2/wo/cg/dg/bo indices stay uniform -> SGPR s_loads.
// Halves exchange gated[] via LDS padded to stride 65 (bank = (lane+hc)%32, 2-way = free).
__global__ __launch_bounds__(256, 4) void k2_gate_out(
    const float* __restrict__ m,
    const float* __restrict__ wg2, const float* __restrict__ cg,
    const float* __restrict__ dg,
    const float* __restrict__ wo,  const float* __restrict__ bo,
    const float* __restrict__ otab,
    float* __restrict__ out)
{
    __shared__ float gbuf[128 * 65];   // 33,280 B

    const int t    = threadIdx.x;
    const int w    = t >> 6;
    const int lane = t & 63;
    const int pair = w >> 1;                      // 0/1: which 64-row group
    const int hf   = w & 1;                       // 0/1: which 32-channel half (wave-uniform)
    const int rowl = pair * 64 + lane;            // local row 0..127
    const int gr   = blockIdx.x * 128 + rowl;     // flat row index = s*384 + r
    const int jb   = hf * 32;

    const float4* xrow = reinterpret_cast<const float4*>(m + (size_t)gr * C_DIM);

    // pass 1: stream full row, LN stats over all 64 ch, accumulate my 32 gate logits
    float raw[32];
    #pragma unroll
    for (int jj = 0; jj < 32; ++jj) raw[jj] = 0.f;
    float sm = 0.f, sq = 0.f;

    #pragma unroll
    for (int c4 = 0; c4 < 16; ++c4){
        float4 f = xrow[c4];
        float xs[4] = {f.x, f.y, f.z, f.w};
        #pragma unroll
        for (int cc = 0; cc < 4; ++cc){
            const int c = c4*4 + cc;
            const float x = xs[cc];
            sm += x;
            sq = fmaf(x, x, sq);
            #pragma unroll
            for (int jj = 0; jj < 32; ++jj)
                raw[jj] = fmaf(x, wg2[c*64 + jb + jj], raw[jj]);
        }
    }

    const float mu = sm * (1.f/64.f);
    const float rs = rsqrtf(fmaf(-mu, mu, sq * (1.f/64.f)) + 1e-5f);

    // gate: logit = rs*(raw - mu*cg) + dg;  gated = o * sigmoid(logit)  -> LDS
    const int r_col = gr % R_DIM;
    const float4* o4 = reinterpret_cast<const float4*>(otab + (size_t)r_col * 64 + jb);
    #pragma unroll
    for (int j4 = 0; j4 < 8; ++j4){
        float4 ov = o4[j4];
        float os[4] = {ov.x, ov.y, ov.z, ov.w};
        #pragma unroll
        for (int q = 0; q < 4; ++q){
            const int jj = j4*4 + q;
            float lg = fmaf(rs, fmaf(-mu, cg[jb+jj], raw[jj]), dg[jb+jj]);
            gbuf[rowl*65 + jb + jj] = os[q] / (1.f + __expf(-lg));
        }
    }
    __syncthreads();

    // out half-row = gated(all 64) @ wo(:, my 32) + bo
    float acc[32];
    #pragma unroll
    for (int jj = 0; jj < 32; ++jj) acc[jj] = bo[jb + jj];
    #pragma unroll
    for (int hc = 0; hc < 64; ++hc){
        const float g = gbuf[rowl*65 + hc];
        #pragma unroll
        for (int jj = 0; jj < 32; ++jj)
            acc[jj] = fmaf(g, wo[hc*64 + jb + jj], acc[jj]);
    }

    float4* orow = reinterpret_cast<float4*>(out + (size_t)gr * C_DIM + jb);
    #pragma unroll
    for (int j4 = 0; j4 < 8; ++j4)
        orow[j4] = make_float4(acc[j4*4+0], acc[j4*4+1], acc[j4*4+2], acc[j4*4+3]);
}

// ------------------------------------------------------------------------------------
extern "C" void kernel_launch(void* const* d_in, const int* in_sizes, int n_in,
                              void* d_out, int out_size, void* d_ws, size_t ws_size,
                              hipStream_t stream)
{
    const float* m    = (const float*)d_in[0];
    const float* mask = (const float*)d_in[1];
    const float* lnw  = (const float*)d_in[2];
    const float* lnb  = (const float*)d_in[3];
    const float* wq   = (const float*)d_in[4];
    const float* wk   = (const float*)d_in[5];
    const float* wv   = (const float*)d_in[6];
    const float* wg   = (const float*)d_in[7];
    const float* bg   = (const float*)d_in[8];
    const float* wo   = (const float*)d_in[9];
    const float* bo   = (const float*)d_in[10];
    float* ws  = (float*)d_ws;
    float* out = (float*)d_out;

    prep_mask<<<dim3((S_DIM * R_DIM) / 256), dim3(256), 0, stream>>>(mask, ws + OFF_MASKT);
    k1_kv_softmax<<<dim3(R_DIM), dim3(256), 0, stream>>>(
        m, lnw, lnb, wq, wk, wv, ws + OFF_MASKT,
        ws + OFF_QRED, ws + OFF_MSUM, ws + OFF_QH, ws + OFF_O);
    // qred region is dead after k1 -> fill it with the fused-LN gate weights
    prep_w<<<dim3(1), dim3(64), 0, stream>>>(
        lnw, lnb, wg, bg, ws + OFF_WG2, ws + OFF_CG, ws + OFF_DG);
    k2_gate_out<<<dim3((S_DIM * R_DIM) / 128), dim3(256), 0, stream>>>(
        m, ws + OFF_WG2, ws + OFF_CG, ws + OFF_DG, wo, bo, ws + OFF_O, out);
}

// Round 5
// 893.765 us; speedup vs baseline: 1.5391x; 1.5391x over previous
//
#include <hip/hip_runtime.h>
#include <stdint.h>

typedef unsigned int u32;
typedef float f32x16 __attribute__((ext_vector_type(16)));
typedef float f32x2  __attribute__((ext_vector_type(2)));

#define S_DIM 2048
#define R_DIM 384
#define C_DIM 64
#define N_ROWS (S_DIM * R_DIM)

// float-offsets into d_ws
#define OFF_MASKT 0          // [384][2048] mask transposed, fp32
#define OFF_QRED  786432     // [384][4][64] per-wave qsum partials (k1-internal)
#define OFF_MSUM  884736     // [384][4]
#define OFF_QH    886272     // [384][64] scaled query
#define OFF_O     910848     // [384][64] per-column attention output o
#define OFF_STAT  935424     // [384][2048][2] (mu, rs) per (r,s) row  (optional, 6.3 MB)
// end with stash: 2508288 floats = 10.03 MB
// qred region is dead after k1 -> reuse it for fused-LN gate weights:
#define OFF_WG2   786432     // [64][64]  lnw[c]*wg[c][j]
#define OFF_CG    790528     // [64]      sum_c wg2[c][j]
#define OFF_DG    790592     // [64]      sum_c lnb[c]*wg[c][j] + bg[j]

__device__ __forceinline__ float bflo(u32 u){ return __uint_as_float(u << 16); }
__device__ __forceinline__ float bfhi(u32 u){ return __uint_as_float(u & 0xffff0000u); }
__device__ __forceinline__ u32 packbf2(float a, float b){
    u32 xa = __float_as_uint(a), xb = __float_as_uint(b);
    u32 ra = (xa + 0x7fffu + ((xa >> 16) & 1u)) >> 16;   // RNE
    u32 rb = (xb + 0x7fffu + ((xb >> 16) & 1u)) >> 16;
    return (ra & 0xffffu) | (rb << 16);
}
__device__ __forceinline__ void u4tof8(uint4 u, float* f){
    f[0]=bflo(u.x); f[1]=bfhi(u.x); f[2]=bflo(u.y); f[3]=bfhi(u.y);
    f[4]=bflo(u.z); f[5]=bfhi(u.z); f[6]=bflo(u.w); f[7]=bfhi(u.w);
}

// make a per-wave-uniform 64-bit address provably uniform (SGPR-allocatable)
__device__ __forceinline__ uint64_t uniform_addr(const void* p){
    uint64_t a = (uint64_t)(uintptr_t)p;
    u32 lo = __builtin_amdgcn_readfirstlane((u32)a);
    u32 hi = __builtin_amdgcn_readfirstlane((u32)(a >> 32));
    return ((uint64_t)hi << 32) | lo;
}

// ---------------- prep: mask [S][R] fp32 -> [R][S] fp32 ----------------------------
__global__ void prep_mask(const float* __restrict__ mask, float* __restrict__ maskT)
{
    const int tid = blockIdx.x * 256 + threadIdx.x;   // over S*R, coalesced read
    const int s = tid / R_DIM;
    const int r = tid - s * R_DIM;
    maskT[(size_t)r * S_DIM + s] = mask[tid];
}

// ---------------- prep: fold LayerNorm into gate matmul ----------------------------
__global__ void prep_w(const float* __restrict__ lnw, const float* __restrict__ lnb,
                       const float* __restrict__ wg,  const float* __restrict__ bg,
                       float* __restrict__ wg2, float* __restrict__ cg,
                       float* __restrict__ dg)
{
    const int j = threadIdx.x;   // 64
    float c_acc = 0.f, d_acc = 0.f;
    for (int c = 0; c < 64; ++c){
        float w  = wg[c*64 + j];
        float w2 = lnw[c] * w;
        wg2[c*64 + j] = w2;
        c_acc += w2;
        d_acc = fmaf(lnb[c], w, d_acc);
    }
    cg[j] = c_acc;
    dg[j] = d_acc + bg[j];
}

// ---------------- K1: per-column LN + k/v + pooled q + softmax + o ------------------
// one block per r; kv kept in LDS (bf16-packed); also stashes (mu,rs) per row for k2
__global__ __launch_bounds__(256, 2) void k1_kv_softmax(
    const float* __restrict__ m,
    const float* __restrict__ lnw, const float* __restrict__ lnb,
    const float* __restrict__ wq,  const float* __restrict__ wk,
    const float* __restrict__ wv,
    const float* __restrict__ maskT,
    float* __restrict__ qred,
    float* __restrict__ msum,
    float* __restrict__ qh,
    float* __restrict__ otab,
    float* __restrict__ mustat)
{
    __shared__ uint4 kv[S_DIM * 2];   // exactly 64 KB: [s][0]=k bf16x8, [s][1]=v bf16x8

    const int t    = threadIdx.x;
    const int r    = blockIdx.x;
    const int w    = t >> 6;
    const int lane = t & 63;

    float qacc[64];
    #pragma unroll
    for (int c = 0; c < 64; ++c) qacc[c] = 0.f;
    float macc = 0.f;

    for (int it = 0; it < 8; ++it){
        const int s = it * 256 + t;
        const float4* mrow = reinterpret_cast<const float4*>(m + ((size_t)s * R_DIM + r) * C_DIM);
        float xn[64];
        #pragma unroll
        for (int q4 = 0; q4 < 16; ++q4){
            float4 f = mrow[q4];
            xn[q4*4+0]=f.x; xn[q4*4+1]=f.y; xn[q4*4+2]=f.z; xn[q4*4+3]=f.w;
        }

        float sm = 0.f, sq = 0.f;
        #pragma unroll
        for (int c = 0; c < 64; ++c){ sm += xn[c]; sq = fmaf(xn[c], xn[c], sq); }
        float mu  = sm * (1.f/64.f);
        float var = fmaf(-mu, mu, sq * (1.f/64.f));
        float rs  = rsqrtf(var + 1e-5f);

        if (mustat)   // stash LN stats for k2 ([r][s] layout -> coalesced 8B/lane)
            *reinterpret_cast<float2*>(mustat + ((size_t)r * S_DIM + s) * 2) =
                make_float2(mu, rs);

        #pragma unroll
        for (int c = 0; c < 64; ++c)
            xn[c] = fmaf((xn[c]-mu)*rs, lnw[c], lnb[c]);

        float mk = maskT[(size_t)r * S_DIM + s];
        macc += mk;
        #pragma unroll
        for (int c = 0; c < 64; ++c) qacc[c] = fmaf(xn[c], mk, qacc[c]);

        float kk[8], vv[8];
        #pragma unroll
        for (int ch = 0; ch < 8; ++ch){ kk[ch]=0.f; vv[ch]=0.f; }
        #pragma unroll
        for (int c = 0; c < 64; ++c){
            float xc = xn[c];
            #pragma unroll
            for (int ch = 0; ch < 8; ++ch){
                kk[ch] = fmaf(xc, wk[c*8 + ch], kk[ch]);
                vv[ch] = fmaf(xc, wv[c*8 + ch], vv[ch]);
            }
        }
        kv[s*2  ] = make_uint4(packbf2(kk[0],kk[1]),packbf2(kk[2],kk[3]),
                               packbf2(kk[4],kk[5]),packbf2(kk[6],kk[7]));
        kv[s*2+1] = make_uint4(packbf2(vv[0],vv[1]),packbf2(vv[2],vv[3]),
                               packbf2(vv[4],vv[5]),packbf2(vv[6],vv[7]));
    }

    // elementwise butterfly reduce qacc over the 64 lanes; lane c keeps channel c
    float myq = 0.f;
    #pragma unroll
    for (int c = 0; c < 64; ++c){
        float v = qacc[c];
        v += __shfl_xor(v, 1);  v += __shfl_xor(v, 2);  v += __shfl_xor(v, 4);
        v += __shfl_xor(v, 8);  v += __shfl_xor(v, 16); v += __shfl_xor(v, 32);
        myq = (lane == c) ? v : myq;
    }
    qred[r*256 + w*64 + lane] = myq;
    {
        float v = macc;
        v += __shfl_xor(v, 1);  v += __shfl_xor(v, 2);  v += __shfl_xor(v, 4);
        v += __shfl_xor(v, 8);  v += __shfl_xor(v, 16); v += __shfl_xor(v, 32);
        if (lane == 0) msum[r*4 + w] = v;
    }
    __threadfence_block();
    __syncthreads();

    // q = (masked-mean(xn) @ wq) * 8^-0.5     (volatile reads: bypass stale L1)
    volatile const float* vqred = qred;
    volatile const float* vmsum = msum;
    if (t < 64){
        float ms   = vmsum[r*4+0] + vmsum[r*4+1] + vmsum[r*4+2] + vmsum[r*4+3];
        float invD = 1.f / (ms + 1e-10f);
        float acc  = 0.f;
        for (int c = 0; c < 64; ++c){
            float qm = (vqred[r*256 + c] + vqred[r*256 + 64 + c] +
                        vqred[r*256 + 128 + c] + vqred[r*256 + 192 + c]) * invD;
            acc = fmaf(qm, wq[c*64 + t], acc);
        }
        qh[r*64 + t] = acc * 0.35355339059327373f;
    }
    __threadfence_block();
    __syncthreads();

    // per-head online softmax over s; 32 lanes per head
    volatile const float* vqh = qh;
    const int h   = t >> 5;
    const int sub = t & 31;
    float qv[8];
    #pragma unroll
    for (int j = 0; j < 8; ++j) qv[j] = vqh[r*64 + h*8 + j];

    float mx = -1e30f, ls = 0.f, oa[8];
    #pragma unroll
    for (int j = 0; j < 8; ++j) oa[j] = 0.f;

    for (int j2 = 0; j2 < 64; ++j2){
        const int s = j2*32 + sub;
        float kf[8]; u4tof8(kv[s*2], kf);
        float mk = maskT[(size_t)r * S_DIM + s];
        float logit = 1e9f * (mk - 1.f);
        #pragma unroll
        for (int j = 0; j < 8; ++j) logit = fmaf(qv[j], kf[j], logit);
        float nm = fmaxf(mx, logit);
        float p  = __expf(logit - nm);
        float cr = __expf(mx - nm);
        float vf[8]; u4tof8(kv[s*2+1], vf);
        ls = fmaf(ls, cr, p);
        #pragma unroll
        for (int j = 0; j < 8; ++j) oa[j] = fmaf(oa[j], cr, p * vf[j]);
        mx = nm;
    }
    #pragma unroll
    for (int xm = 16; xm >= 1; xm >>= 1){
        float m2 = __shfl_xor(mx, xm);
        float l2 = __shfl_xor(ls, xm);
        float nm = fmaxf(mx, m2);
        float c1 = __expf(mx - nm);
        float c2 = __expf(m2 - nm);
        ls = ls*c1 + l2*c2;
        #pragma unroll
        for (int j = 0; j < 8; ++j){
            float o2 = __shfl_xor(oa[j], xm);
            oa[j] = oa[j]*c1 + o2*c2;
        }
        mx = nm;
    }
    if (sub == 0){
        float inv = 1.f / ls;
        #pragma unroll
        for (int j = 0; j < 8; ++j) otab[r*64 + h*8 + j] = oa[j] * inv;
    }
}

// ---------------- K2: weight-stationary gate + output projection --------------------
// Lane j owns column j of wg2 and wo in VGPRs (loaded once per 256 rows).
// Per row: x[64] -> SGPRs via s_load_dwordx16 (address made provably uniform with
// readfirstlane), FMAs take the SGPR operand directly -> zero vector loads in the
// inner loops. gated[] redistributed via v_readlane (VALU pipe, not LDS).
// Stores 4B/lane = 256B/wave coalesced.
template<int STASH>
__global__ __launch_bounds__(256, 3) void k2_gate_out(
    const float* __restrict__ m,
    const float* __restrict__ wg2, const float* __restrict__ cg,
    const float* __restrict__ dg,
    const float* __restrict__ wo,  const float* __restrict__ bo,
    const float* __restrict__ otab,
    const float* __restrict__ mustat,
    float* __restrict__ out)
{
    const int lane = threadIdx.x & 63;
    const int wid  = blockIdx.x * 4 + (threadIdx.x >> 6);   // 3072 waves total

    float wgc[64], woc[64];
    #pragma unroll
    for (int c = 0; c < 64; ++c) wgc[c] = wg2[c*64 + lane];
    #pragma unroll
    for (int c = 0; c < 64; ++c) woc[c] = wo[c*64 + lane];
    const float cgl = cg[lane], dgl = dg[lane], bol = bo[lane];

    const int base = wid * (N_ROWS / 3072);                 // 256 contiguous rows/wave
    #pragma unroll 1
    for (int it = 0; it < N_ROWS / 3072; ++it){
        const int n = base + it;
        const int s = n / R_DIM;
        const int r = n - s * R_DIM;

        const uint64_t xa = uniform_addr(m + (size_t)n * C_DIM);
        f32x16 x0, x1, x2, x3;
        float mu, rs, raw;

        if (STASH){
            const uint64_t sa = uniform_addr(mustat + ((size_t)r * S_DIM + s) * 2);
            f32x2 st;
            asm volatile(
                "s_load_dwordx16 %0, %3, 0x0\n\t"
                "s_load_dwordx16 %1, %3, 0x40\n\t"
                "s_load_dwordx2  %2, %4, 0x0\n\t"
                "s_waitcnt lgkmcnt(0)"
                : "=&s"(x0), "=&s"(x1), "=&s"(st)
                : "s"(xa), "s"(sa));
            mu = st[0]; rs = st[1];
            float r0 = 0.f, r1 = 0.f;
            #pragma unroll
            for (int c = 0; c < 16; ++c){
                r0 = fmaf(x0[c], wgc[c],    r0);
                r1 = fmaf(x1[c], wgc[16+c], r1);
            }
            asm volatile(
                "s_load_dwordx16 %0, %2, 0x80\n\t"
                "s_load_dwordx16 %1, %2, 0xc0\n\t"
                "s_waitcnt lgkmcnt(0)"
                : "=&s"(x2), "=&s"(x3)
                : "s"(xa));
            float r2 = 0.f, r3 = 0.f;
            #pragma unroll
            for (int c = 0; c < 16; ++c){
                r2 = fmaf(x2[c], wgc[32+c], r2);
                r3 = fmaf(x3[c], wgc[48+c], r3);
            }
            raw = (r0+r1)+(r2+r3);
        } else {
            asm volatile(
                "s_load_dwordx16 %0, %2, 0x0\n\t"
                "s_load_dwordx16 %1, %2, 0x40\n\t"
                "s_waitcnt lgkmcnt(0)"
                : "=&s"(x0), "=&s"(x1)
                : "s"(xa));
            float r0=0.f, r1=0.f, s0=0.f, s1=0.f, q0=0.f, q1=0.f;
            #pragma unroll
            for (int c = 0; c < 16; ++c){
                r0 = fmaf(x0[c], wgc[c],    r0);
                r1 = fmaf(x1[c], wgc[16+c], r1);
                s0 += x0[c]; q0 = fmaf(x0[c], x0[c], q0);
                s1 += x1[c]; q1 = fmaf(x1[c], x1[c], q1);
            }
            asm volatile(
                "s_load_dwordx16 %0, %2, 0x80\n\t"
                "s_load_dwordx16 %1, %2, 0xc0\n\t"
                "s_waitcnt lgkmcnt(0)"
                : "=&s"(x2), "=&s"(x3)
                : "s"(xa));
            float r2=0.f, r3=0.f, s2=0.f, s3=0.f, q2=0.f, q3=0.f;
            #pragma unroll
            for (int c = 0; c < 16; ++c){
                r2 = fmaf(x2[c], wgc[32+c], r2);
                r3 = fmaf(x3[c], wgc[48+c], r3);
                s2 += x2[c]; q2 = fmaf(x2[c], x2[c], q2);
                s3 += x3[c]; q3 = fmaf(x3[c], x3[c], q3);
            }
            raw = (r0+r1)+(r2+r3);
            float sm = (s0+s1)+(s2+s3), sq = (q0+q1)+(q2+q3);
            mu = sm * (1.f/64.f);
            rs = rsqrtf(fmaf(-mu, mu, sq * (1.f/64.f)) + 1e-5f);
        }

        const float lg    = fmaf(rs, fmaf(-mu, cgl, raw), dgl);
        const float oj    = otab[r*64 + lane];
        const float gated = oj / (1.f + __expf(-lg));

        // redistribute gated[] to SGPRs (VALU readlane, not LDS pipe)
        float sg[64];
        #pragma unroll
        for (int i = 0; i < 64; ++i)
            sg[i] = __uint_as_float(__builtin_amdgcn_readlane(__float_as_uint(gated), i));

        // out_j = bo_j + sum_hc gated[hc] * wo[hc][j]
        float a0=bol, a1=0.f, a2=0.f, a3=0.f;
        #pragma unroll
        for (int hc = 0; hc < 16; ++hc){
            a0 = fmaf(sg[hc],    woc[hc],    a0);
            a1 = fmaf(sg[16+hc], woc[16+hc], a1);
            a2 = fmaf(sg[32+hc], woc[32+hc], a2);
            a3 = fmaf(sg[48+hc], woc[48+hc], a3);
        }
        out[(size_t)n * C_DIM + lane] = (a0+a1)+(a2+a3);
    }
}

// ------------------------------------------------------------------------------------
extern "C" void kernel_launch(void* const* d_in, const int* in_sizes, int n_in,
                              void* d_out, int out_size, void* d_ws, size_t ws_size,
                              hipStream_t stream)
{
    const float* m    = (const float*)d_in[0];
    const float* mask = (const float*)d_in[1];
    const float* lnw  = (const float*)d_in[2];
    const float* lnb  = (const float*)d_in[3];
    const float* wq   = (const float*)d_in[4];
    const float* wk   = (const float*)d_in[5];
    const float* wv   = (const float*)d_in[6];
    const float* wg   = (const float*)d_in[7];
    const float* bg   = (const float*)d_in[8];
    const float* wo   = (const float*)d_in[9];
    const float* bo   = (const float*)d_in[10];
    float* ws  = (float*)d_ws;
    float* out = (float*)d_out;

    const bool stash = ws_size >= (size_t)(OFF_STAT + (size_t)N_ROWS * 2) * sizeof(float);
    float* mustat = stash ? (ws + OFF_STAT) : nullptr;

    prep_mask<<<dim3((S_DIM * R_DIM) / 256), dim3(256), 0, stream>>>(mask, ws + OFF_MASKT);
    k1_kv_softmax<<<dim3(R_DIM), dim3(256), 0, stream>>>(
        m, lnw, lnb, wq, wk, wv, ws + OFF_MASKT,
        ws + OFF_QRED, ws + OFF_MSUM, ws + OFF_QH, ws + OFF_O, mustat);
    // qred region is dead after k1 -> fill it with the fused-LN gate weights
    prep_w<<<dim3(1), dim3(64), 0, stream>>>(
        lnw, lnb, wg, bg, ws + OFF_WG2, ws + OFF_CG, ws + OFF_DG);
    if (stash)
        k2_gate_out<1><<<dim3(768), dim3(256), 0, stream>>>(
            m, ws + OFF_WG2, ws + OFF_CG, ws + OFF_DG, wo, bo, ws + OFF_O, mustat, out);
    else
        k2_gate_out<0><<<dim3(768), dim3(256), 0, stream>>>(
            m, ws + OFF_WG2, ws + OFF_CG, ws + OFF_DG, wo, bo, ws + OFF_O, nullptr, out);
}